// Round 9
// baseline (5704.543 us; speedup 1.0000x reference)
//
#include <hip/hip_runtime.h>
#include <hip/hip_bf16.h>

// RNNColorbot round 12: persistent kernel with CACHE-ROUTED coherence.
// History: multi-launch floor ~28us/launch is launch-boundary cache churn
// (r1/r2/r8: in-kernel work irrelevant). r6 persistent PASSED (structure
// correct) but agent acquire-fence buffer_inv'd L2 every slot -> 17.6MB
// weight refetch/slot -> 13.8ms. This round keeps r6's skeleton and removes
// the inv entirely by routing the ONLY cross-XCD data (h, hidden) around
// the incoherent caches:
//   - h loads:  global_load_lds aux=17 (SC0|SC1) = system-coherent bypass
//   - h/hidden stores: __hip_atomic_store SYSTEM relaxed = write-through
//   - barrier: per-wave vmcnt(0) drain -> syncthreads -> tid0 system-scope
//     arrive+spin (guarded) -> syncthreads. NO fences, NO wbl2, NO inv.
// Weights stay L2-resident for all 128 steps; C stays dirty-local.
// Step body (BK=128, gate-16 permutation, swizzled LDS + LDS-DMA x16,
// register-resident cell update, sort + early-exit) unchanged from r6.

typedef __hip_bfloat16 bf16;
typedef __attribute__((ext_vector_type(8))) short bfrag8;   // 8 bf16 = 4 VGPRs
typedef __attribute__((ext_vector_type(4))) float accf4;    // MFMA accum

#define BATCH 512
#define TSTEPS 128
#define DIN 256
#define H 1024
#define NG 4096   // 4*H gate columns
#define NBLK 512  // persistent grid

__device__ __forceinline__ float sigm(float x) { return 1.0f / (1.0f + __expf(-x)); }
__device__ __forceinline__ float tanh_f(float x) {
    float a = fabsf(x);
    float e = __expf(-2.0f * a);
    float t = (1.0f - e) / (1.0f + e);
    return x < 0.0f ? -t : t;
}
__device__ __forceinline__ unsigned short bfr16(float x) {
    bf16 h = __float2bfloat16(x);
    return *(unsigned short*)&h;
}
// async global->LDS, 16B/lane, default policy (weights/x: L2-cached).
__device__ __forceinline__ void gll16(const void* g, void* l) {
    __builtin_amdgcn_global_load_lds(
        (const __attribute__((address_space(1))) unsigned int*)g,
        (__attribute__((address_space(3))) unsigned int*)l, 16, 0, 0);
}
// async global->LDS, 16B/lane, aux=17 = SC0|SC1 (gfx940+ CPol: SC0=1,SC1=16):
// system-coherent read, bypasses local L1/L2, reads MALL. Used ONLY for h.
__device__ __forceinline__ void gll16_sys(const void* g, void* l) {
    __builtin_amdgcn_global_load_lds(
        (const __attribute__((address_space(1))) unsigned int*)g,
        (__attribute__((address_space(3))) unsigned int*)l, 16, 0, 17);
}

// ---------------------------------------------------------------------------
// Repack [W;U] (fp32, K x 4096) -> Bp bf16 [KT][4096][128], gate-16 permuted:
//   new col n -> orig ((n>>4)&3)*1024 + (n>>7)*32 + ((n>>6)&1)*16 + (n&15)
// XOR-swizzled in 16B chunks: chunk kc of row n stored at pos kc ^ (n&7),
// so global layout == LDS layout and global_load_lds copies linearly.
// ---------------------------------------------------------------------------
__global__ void k_repack(const float* __restrict__ W, const float* __restrict__ U,
                         bf16* __restrict__ Bp, int KIN)
{
    __shared__ float tile[128][65];
    int kt = blockIdx.x, nt = blockIdx.y;
    int lane = threadIdx.x;     // 64 threads
    int n = nt * 64 + lane;
    int orig = ((n >> 4) & 3) * 1024 + (n >> 7) * 32 + ((n >> 6) & 1) * 16 + (n & 15);
    for (int j = 0; j < 128; ++j) {
        int k = kt * 128 + j;
        tile[j][lane] = (k < KIN) ? W[(size_t)k * NG + orig]
                                  : U[(size_t)(k - KIN) * NG + orig];
    }
    __syncthreads();
    for (int u = 0; u < 16; ++u) {
        int cid = u * 64 + lane;           // 1024 chunks
        int nloc = cid >> 4;
        int pos = cid & 15;
        int nn = nt * 64 + nloc;
        int kc = pos ^ (nn & 7);           // logical chunk stored here
        alignas(16) unsigned short pk[8];
        #pragma unroll
        for (int jj = 0; jj < 8; ++jj) pk[jj] = bfr16(tile[kc * 8 + jj][nloc]);
        *(int4*)(Bp + ((size_t)kt * NG + nn) * 128 + pos * 8) = *(int4*)pk;
    }
}

// ---------------------------------------------------------------------------
// Counting sort of the 512 rows by descending seqlen.
//   perm[pos] = original row index; cnt[t] = #rows with len > t
// ---------------------------------------------------------------------------
__global__ void k_sort(const int* __restrict__ seqlen, int* __restrict__ perm,
                       int* __restrict__ cnt)
{
    __shared__ int hist[129];
    __shared__ int base[129];
    __shared__ int cur[129];
    int tid = threadIdx.x;          // 512 threads
    if (tid < 129) { hist[tid] = 0; cur[tid] = 0; }
    __syncthreads();
    int len = seqlen[tid];          // len in [1,128]
    atomicAdd(&hist[len], 1);
    __syncthreads();
    if (tid == 0) {
        int acc = 0;
        for (int l = 128; l >= 1; --l) { base[l] = acc; acc += hist[l]; }
        base[0] = acc;              // = 512
    }
    __syncthreads();
    int pos = base[len] + atomicAdd(&cur[len], 1);
    perm[pos] = tid;
    if (tid < 128) cnt[tid] = base[tid];   // #rows with len > t
}

// ---------------------------------------------------------------------------
// Shared step body: one (job, btile, ntile) tile of one LSTM layer-step.
// ---------------------------------------------------------------------------
struct StepJob {
    const float* Xf;      // L1: fp32 x source (chars + t*DIN), else null
    const bf16* A0;       // first-K bf16 source (L2: h1[t]); swizzled
    const bf16* A1;       // recurrent h-prev source; swizzled
    const bf16* Bp;       // weights (gate-16 permuted + swizzled)
    const float* bias;    // [4096] original gate order
    float* C;             // fp32 cell state [512][1024] (perm space)
    bf16* Hout;           // h output, written SWIZZLED (perm space)
    float* hidden;        // L2: fp32 gather target (linear, ORIGINAL space)
    const int* seqlen;    // L2 (original space)
    const int* perm;      // perm[r] = original row of permuted row r
    int xstride;          // elems per row of Xf
    int ksplit;           // 256 (L1) / 1024 (L2)
    int KT;               // 10 / 16 rounds of BK=128
    int t;
};

__device__ __forceinline__ void step_body(
    const StepJob& jb, bf16* Alds, bf16* Blds,
    int b0, int n0, int ntile, int tid, int wv, int lane,
    int mw, int nw, int c, int q, bool is_l2)
{
    const accf4 zero4 = {0.f, 0.f, 0.f, 0.f};
    accf4 acc[2][4];
    #pragma unroll
    for (int i = 0; i < 2; ++i)
        #pragma unroll
        for (int j = 0; j < 4; ++j) acc[i][j] = zero4;

    for (int kt = 0; kt < jb.KT; ++kt) {
        int k0 = kt << 7;
        // ---- stage A tile [64 rows][128 k] (swizzled) ----
        if (jb.Xf && k0 < jb.ksplit) {
            // fp32 -> bf16 convert path (L1 x-tiles; kt 0..1), perm-gathered
            #pragma unroll
            for (int uu = 0; uu < 4; ++uu) {
                int u = uu * 256 + tid;            // chunk id 0..1023
                int r = u >> 4;                    // row (perm space)
                int pos = u & 15;                  // swizzled position
                int kc = pos ^ (r & 7);            // logical k-chunk
                const float* src = jb.Xf + (size_t)jb.perm[b0 + r] * jb.xstride + k0 + kc * 8;
                float4 va = *(const float4*)src;
                float4 vb = *(const float4*)(src + 4);
                alignas(16) unsigned short pk[8];
                pk[0] = bfr16(va.x); pk[1] = bfr16(va.y);
                pk[2] = bfr16(va.z); pk[3] = bfr16(va.w);
                pk[4] = bfr16(vb.x); pk[5] = bfr16(vb.y);
                pk[6] = bfr16(vb.z); pk[7] = bfr16(vb.w);
                *(int4*)((char*)Alds + u * 16) = *(int4*)pk;
            }
        } else {
            const bf16* Asrc; int kk0;
            if (k0 < jb.ksplit) { Asrc = jb.A0; kk0 = k0; }
            else                { Asrc = jb.A1; kk0 = k0 - jb.ksplit; }
            // h tiles: cross-XCD data -> system-coherent bypass DMA
            #pragma unroll
            for (int cc = 0; cc < 4; ++cc) {
                int ob = wv * 4096 + cc * 1024;
                int o = ob + lane * 16;
                int r = o >> 8;
                const char* g = (const char*)Asrc + (size_t)(b0 + r) * (H * 2) + kk0 * 2 + (o & 255);
                gll16_sys(g, (char*)Alds + ob);
            }
        }
        // ---- stage B tile: contiguous 32 KB (pre-swizzled, L2-resident) ----
        const char* Bg = (const char*)jb.Bp + ((size_t)kt * NG + n0) * 256;
        #pragma unroll
        for (int cc = 0; cc < 8; ++cc) {
            int ob = wv * 8192 + cc * 1024;
            gll16(Bg + ob + lane * 16, (char*)Blds + ob);
        }
        __syncthreads();
        // ---- MFMA: 4 k-steps of 32, swizzle-decoded fragment reads ----
        #pragma unroll
        for (int kk = 0; kk < 128; kk += 32) {
            int kc = (kk >> 3) + q;                  // logical chunk 0..15
            int ra = mw + c;
            int pa = (kc ^ (ra & 7)) << 3;           // (ra+16)&7 == ra&7
            bfrag8 af0 = *(const bfrag8*)(Alds + ra * 128 + pa);
            bfrag8 af1 = *(const bfrag8*)(Alds + (ra + 16) * 128 + pa);
            #pragma unroll
            for (int nt = 0; nt < 4; ++nt) {
                int nn = nw + nt * 16 + c;
                bfrag8 bfv = *(const bfrag8*)(Blds + nn * 128 + ((kc ^ (nn & 7)) << 3));
                acc[0][nt] = __builtin_amdgcn_mfma_f32_16x16x32_bf16(af0, bfv, acc[0][nt], 0, 0, 0);
                acc[1][nt] = __builtin_amdgcn_mfma_f32_16x16x32_bf16(af1, bfv, acc[1][nt], 0, 0, 0);
            }
        }
        __syncthreads();
    }

    // ---- register-resident cell update ----
    // acc[mt][gate][reg]: row = mw+mt*16+q*4+reg, hcol = ntile*32+(wv>>1)*16+c
    int hcol = ntile * 32 + (wv >> 1) * 16 + c;
    float bi_ = jb.bias[hcol],         bf_ = jb.bias[H + hcol];
    float bg_ = jb.bias[2 * H + hcol], bo_ = jb.bias[3 * H + hcol];
    int seg = hcol & ~127;
    int kc_ = (hcol & 127) >> 3;
    int jl = hcol & 7;
    #pragma unroll
    for (int mt = 0; mt < 2; ++mt) {
        #pragma unroll
        for (int reg = 0; reg < 4; ++reg) {
            int b = b0 + mw + mt * 16 + q * 4 + reg;
            float ig = sigm(acc[mt][0][reg] + bi_);
            float fg = sigm(acc[mt][1][reg] + bf_);
            float gv = tanh_f(acc[mt][2][reg] + bg_);
            float og = sigm(acc[mt][3][reg] + bo_);
            size_t ci = (size_t)b * H + hcol;
            float cv = fg * jb.C[ci] + ig * gv;
            jb.C[ci] = cv;                      // block-private, stays L2-dirty
            float h = og * tanh_f(cv);
            // h: write-through to coherent point (consumers bypass-read MALL)
            unsigned short hb = bfr16(h);
            unsigned short* hp = (unsigned short*)(jb.Hout
                + (size_t)b * H + seg + ((kc_ ^ (b & 7)) << 3) + jl);
            __hip_atomic_store(hp, hb, __ATOMIC_RELAXED, __HIP_MEMORY_SCOPE_SYSTEM);
            if (is_l2) {
                int pb = jb.perm[b];
                if (jb.seqlen[pb] - 1 == jb.t)
                    __hip_atomic_store(&jb.hidden[(size_t)pb * H + hcol], h,
                                       __ATOMIC_RELAXED, __HIP_MEMORY_SCOPE_SYSTEM);
            }
        }
    }
}

// ---------------------------------------------------------------------------
// Persistent kernel, plain launch. 512 blocks x 256 threads, 2 blocks/CU
// (guaranteed by __launch_bounds__(256,2) + 48 KB LDS/block; r6 proved
// co-residency + completion). jidx0 = L2 at t=s-1, jidx1 = L1 at t=s.
// Barrier: per-wave vmcnt(0) drain (WT stores acked at coherent point) ->
// syncthreads -> tid0 system-scope arrive + guarded spin -> syncthreads.
// ---------------------------------------------------------------------------
struct PersistArgs {
    const float* chars;
    const int* seqlen;
    const float* b1; const float* b2;
    const bf16* Bp1; const bf16* Bp2;
    float* c1; float* c2;
    bf16* h1; bf16* h2;
    float* hidden;
    const int* perm; const int* cnt;
    unsigned* bar;
};

__global__ __launch_bounds__(256, 2) void k_persist(PersistArgs P)
{
    __shared__ __align__(16) bf16 Alds[64 * 128];    // 16 KB, swizzled
    __shared__ __align__(16) bf16 Blds[128 * 128];   // 32 KB, swizzled

    int jidx = blockIdx.x >> 8;
    int bi = blockIdx.x & 255;
    int xcd = bi & 7;
    int sl = bi >> 3;
    int btr = sl >> 2;
    int btile = jidx ? (7 - btr) : btr;
    int ntile = ((sl & 3) << 3) | xcd;
    int b0 = btile * 64;

    int tid = threadIdx.x;
    int wv = tid >> 6, lane = tid & 63;
    int n0 = ntile * 128;
    int mw = (wv & 1) * 32;
    int nw = (wv >> 1) * 64;
    int c = lane & 15, q = lane >> 4;
    const size_t HS = (size_t)BATCH * H;

    StepJob J;
    J.perm = P.perm;
    if (jidx == 1) {           // L1
        J.Bp = P.Bp1; J.bias = P.b1; J.C = P.c1;
        J.hidden = nullptr; J.seqlen = nullptr;
        J.xstride = TSTEPS * DIN; J.ksplit = 256; J.KT = 10;
    } else {                   // L2
        J.Bp = P.Bp2; J.bias = P.b2; J.C = P.c2;
        J.hidden = P.hidden; J.seqlen = P.seqlen;
        J.xstride = 0; J.ksplit = 1024; J.KT = 16;
    }

    for (int s = 0; s <= TSTEPS; ++s) {
        bool active;
        if (jidx == 0) {              // L2 at t = s-1
            active = (s >= 1);
            int t = s - 1;
            J.t = t;
            J.Xf = nullptr;
            J.A0 = P.h1 + (size_t)(t & 1) * HS;         // h1[t]
            J.A1 = P.h2 + (size_t)((t + 1) & 1) * HS;   // h2[t-1]
            J.Hout = P.h2 + (size_t)(t & 1) * HS;
        } else {                      // L1 at t = s
            active = (s < TSTEPS);
            int t = s;
            J.t = t;
            J.Xf = P.chars + (size_t)t * DIN;
            J.A0 = nullptr;
            J.A1 = P.h1 + (size_t)((t + 1) & 1) * HS;   // h1[t-1]
            J.Hout = P.h1 + (size_t)(t & 1) * HS;
        }
        if (active && b0 < P.cnt[J.t]) {
            step_body(J, Alds, Blds, b0, n0, ntile, tid, wv, lane, mw, nw, c, q,
                      jidx == 0);
        }

        // ---- device-wide barrier between slots (no fences, no inv) ----
        if (s < TSTEPS) {
            // per-wave: WT h stores acked at coherent point
            asm volatile("s_waitcnt vmcnt(0)" ::: "memory");
            __syncthreads();
            if (tid == 0) {
                __hip_atomic_fetch_add(P.bar, 1u, __ATOMIC_RELAXED,
                                       __HIP_MEMORY_SCOPE_SYSTEM);
                unsigned target = (unsigned)(s + 1) * NBLK;
                int guard = 0;
                while (__hip_atomic_load(P.bar, __ATOMIC_RELAXED,
                                         __HIP_MEMORY_SCOPE_SYSTEM) < target) {
                    __builtin_amdgcn_s_sleep(1);
                    if (++guard > 100000) break;   // ~2.7 ms: degrade, don't hang
                }
            }
            __syncthreads();
        }
    }
}

// ---------------------------------------------------------------------------
// out[b][l] = relu(hidden[b]·Wd[:,l] + bd[l]), 512 blocks x 1 wave
// ---------------------------------------------------------------------------
__global__ void k_final(const float* __restrict__ hidden, const float* __restrict__ Wd,
                        const float* __restrict__ bd, float* __restrict__ out)
{
    int b = blockIdx.x;
    int l = threadIdx.x;
    float p0 = 0.f, p1 = 0.f, p2 = 0.f;
    for (int jj = l; jj < H; jj += 64) {
        float hv = hidden[(size_t)b * H + jj];
        p0 += hv * Wd[jj * 3 + 0];
        p1 += hv * Wd[jj * 3 + 1];
        p2 += hv * Wd[jj * 3 + 2];
    }
    #pragma unroll
    for (int off = 32; off > 0; off >>= 1) {
        p0 += __shfl_down(p0, off);
        p1 += __shfl_down(p1, off);
        p2 += __shfl_down(p2, off);
    }
    if (l == 0) {
        out[b * 3 + 0] = fmaxf(p0 + bd[0], 0.f);
        out[b * 3 + 1] = fmaxf(p1 + bd[1], 0.f);
        out[b * 3 + 2] = fmaxf(p2 + bd[2], 0.f);
    }
}

extern "C" void kernel_launch(void* const* d_in, const int* in_sizes, int n_in,
                              void* d_out, int out_size, void* d_ws, size_t ws_size,
                              hipStream_t stream)
{
    const float* chars = (const float*)d_in[0];
    const int* seqlen  = (const int*)d_in[1];
    const float* W1 = (const float*)d_in[2];
    const float* U1 = (const float*)d_in[3];
    const float* b1 = (const float*)d_in[4];
    const float* W2 = (const float*)d_in[5];
    const float* U2 = (const float*)d_in[6];
    const float* b2 = (const float*)d_in[7];
    const float* Wd = (const float*)d_in[8];
    const float* bd = (const float*)d_in[9];
    float* out = (float*)d_out;

    char* ws = (char*)d_ws;
    size_t off = 0;
    bf16* Bp1 = (bf16*)(ws + off); off += (size_t)10 * NG * 128 * 2;  // 10.0 MB
    bf16* Bp2 = (bf16*)(ws + off); off += (size_t)16 * NG * 128 * 2;  // 16.0 MB
    bf16* h1  = (bf16*)(ws + off); off += (size_t)2 * BATCH * H * 2;  // 2 MB ping-pong
    bf16* h2  = (bf16*)(ws + off); off += (size_t)2 * BATCH * H * 2;  // 2 MB
    float* c1 = (float*)(ws + off); off += (size_t)BATCH * H * 4;     // 2 MB
    float* c2 = (float*)(ws + off); off += (size_t)BATCH * H * 4;     // 2 MB
    float* hidden = (float*)(ws + off); off += (size_t)BATCH * H * 4; // 2 MB
    int* perm = (int*)(ws + off); off += BATCH * 4;                   // 2 KB
    int* cntA = (int*)(ws + off); off += TSTEPS * 4;                  // 512 B
    unsigned* bar = (unsigned*)(ws + off); off += 256;                // barrier
    if (ws_size < off) return;  // ~36 MB needed

    (void)hipMemsetAsync(h1, 0, (size_t)2 * BATCH * H * 2, stream);
    (void)hipMemsetAsync(h2, 0, (size_t)2 * BATCH * H * 2, stream);
    (void)hipMemsetAsync(c1, 0, (size_t)BATCH * H * 4, stream);
    (void)hipMemsetAsync(c2, 0, (size_t)BATCH * H * 4, stream);
    (void)hipMemsetAsync(bar, 0, 256, stream);

    k_repack<<<dim3(10, 64), 64, 0, stream>>>(W1, U1, Bp1, 256);
    k_repack<<<dim3(16, 64), 64, 0, stream>>>(W2, U2, Bp2, 1024);
    k_sort<<<1, 512, 0, stream>>>(seqlen, perm, cntA);

    PersistArgs P;
    P.chars = chars; P.seqlen = seqlen;
    P.b1 = b1; P.b2 = b2;
    P.Bp1 = Bp1; P.Bp2 = Bp2;
    P.c1 = c1; P.c2 = c2;
    P.h1 = h1; P.h2 = h2;
    P.hidden = hidden;
    P.perm = perm; P.cnt = cntA;
    P.bar = bar;
    k_persist<<<dim3(NBLK), dim3(256), 0, stream>>>(P);

    k_final<<<512, 64, 0, stream>>>(hidden, Wd, bd, out);
}

// Round 10
// 4552.522 us; speedup vs baseline: 1.2531x; 1.2531x over previous
//
#include <hip/hip_runtime.h>
#include <hip/hip_bf16.h>

// RNNColorbot round 13: persistent kernel, pipelined rounds + flag barrier.
// r9 proved the coherence routing (aux=17 bypass h loads, WT h stores, no
// fences) CORRECT but slow (44us/slot = serial vmcnt(0) rounds ~36us +
// contended single-counter barrier ~8us). This round:
//  - BK=64, A/B both LDS double-buffered (48KB), counted s_waitcnt vmcnt(6)
//    per round + raw s_barrier -> loads span rounds (T3/T4 pattern)
//  - x pre-converted once to swizzled bf16 (k_xprep) -> uniform DMA staging
//  - next-slot B(0) prefetch before the grid barrier
//  - flag barrier: per-block 128B-line flags (WT stores), master block
//    (earliest-dying tile, compute-free most of the run) polls with 256
//    threads, WT-stores a release word; no atomic RMW contention.
// Identity mapping, sort+early-exit, gate-16 permutation, cell update: as r9.

typedef __hip_bfloat16 bf16;
typedef __attribute__((ext_vector_type(8))) short bfrag8;   // 8 bf16 = 4 VGPRs
typedef __attribute__((ext_vector_type(4))) float accf4;    // MFMA accum

#define BATCH 512
#define TSTEPS 128
#define DIN 256
#define H 1024
#define NG 4096   // 4*H gate columns
#define NBLK 512
#define MASTER 256   // jidx1,bi=0 -> btile 7: dies earliest, cheap poller

__device__ __forceinline__ float sigm(float x) { return 1.0f / (1.0f + __expf(-x)); }
__device__ __forceinline__ float tanh_f(float x) {
    float a = fabsf(x);
    float e = __expf(-2.0f * a);
    float t = (1.0f - e) / (1.0f + e);
    return x < 0.0f ? -t : t;
}
__device__ __forceinline__ unsigned short bfr16(float x) {
    bf16 h = __float2bfloat16(x);
    return *(unsigned short*)&h;
}
// async global->LDS, 16B/lane, default policy (weights/x: L2-cached)
__device__ __forceinline__ void gll16(const void* g, void* l) {
    __builtin_amdgcn_global_load_lds(
        (const __attribute__((address_space(1))) unsigned int*)g,
        (__attribute__((address_space(3))) unsigned int*)l, 16, 0, 0);
}
// aux=17 = SC0|SC1: system-coherent bypass read (MALL). h tiles only.
__device__ __forceinline__ void gll16_sys(const void* g, void* l) {
    __builtin_amdgcn_global_load_lds(
        (const __attribute__((address_space(1))) unsigned int*)g,
        (__attribute__((address_space(3))) unsigned int*)l, 16, 0, 17);
}

// ---------------------------------------------------------------------------
// Repack [W;U] (fp32, K x 4096) -> Bp bf16 [KT128][4096][128], gate-16
// permuted, XOR-swizzled in 16B chunks (chunk kc of row n at pos kc^(n&7),
// bit3 kept -> each 128B half-row is self-contained for BK=64).
// ---------------------------------------------------------------------------
__global__ void k_repack(const float* __restrict__ W, const float* __restrict__ U,
                         bf16* __restrict__ Bp, int KIN)
{
    __shared__ float tile[128][65];
    int kt = blockIdx.x, nt = blockIdx.y;
    int lane = threadIdx.x;     // 64 threads
    int n = nt * 64 + lane;
    int orig = ((n >> 4) & 3) * 1024 + (n >> 7) * 32 + ((n >> 6) & 1) * 16 + (n & 15);
    for (int j = 0; j < 128; ++j) {
        int k = kt * 128 + j;
        tile[j][lane] = (k < KIN) ? W[(size_t)k * NG + orig]
                                  : U[(size_t)(k - KIN) * NG + orig];
    }
    __syncthreads();
    for (int u = 0; u < 16; ++u) {
        int cid = u * 64 + lane;
        int nloc = cid >> 4;
        int pos = cid & 15;
        int nn = nt * 64 + nloc;
        int kc = pos ^ (nn & 7);
        alignas(16) unsigned short pk[8];
        #pragma unroll
        for (int jj = 0; jj < 8; ++jj) pk[jj] = bfr16(tile[kc * 8 + jj][nloc]);
        *(int4*)(Bp + ((size_t)kt * NG + nn) * 128 + pos * 8) = *(int4*)pk;
    }
}

// ---------------------------------------------------------------------------
// Counting sort by descending seqlen: perm[pos]=orig row; cnt[t]=#len>t.
// ---------------------------------------------------------------------------
__global__ void k_sort(const int* __restrict__ seqlen, int* __restrict__ perm,
                       int* __restrict__ cnt)
{
    __shared__ int hist[129];
    __shared__ int base[129];
    __shared__ int cur[129];
    int tid = threadIdx.x;          // 512 threads
    if (tid < 129) { hist[tid] = 0; cur[tid] = 0; }
    __syncthreads();
    int len = seqlen[tid];
    atomicAdd(&hist[len], 1);
    __syncthreads();
    if (tid == 0) {
        int acc = 0;
        for (int l = 128; l >= 1; --l) { base[l] = acc; acc += hist[l]; }
        base[0] = acc;
    }
    __syncthreads();
    int pos = base[len] + atomicAdd(&cur[len], 1);
    perm[pos] = tid;
    if (tid < 128) cnt[tid] = base[tid];
}

// ---------------------------------------------------------------------------
// Pre-convert chars -> xbf [t][512(perm)][256] bf16, A-swizzled (chunk kc of
// row r at pos (kc&8)|((kc&7)^(r&7)) within each 128-k block) so the LSTM
// kernel stages x identically to h tiles (linear DMA copy).
// ---------------------------------------------------------------------------
__global__ void k_xprep(const float* __restrict__ chars, const int* __restrict__ perm,
                        bf16* __restrict__ xbf)
{
    int t = blockIdx.x;                          // 0..127
    int cid = blockIdx.y * 256 + threadIdx.x;    // 0..16383
    int r = cid >> 5;                            // perm-space row
    int g = (cid >> 4) & 1;                      // 128-k block
    int p = cid & 15;                            // stored position
    int kc = (p & 8) | ((p & 7) ^ (r & 7));      // logical chunk
    const float* src = chars + (size_t)perm[r] * (TSTEPS * DIN) + t * DIN + g * 128 + kc * 8;
    float4 va = *(const float4*)src;
    float4 vb = *(const float4*)(src + 4);
    alignas(16) unsigned short pk[8];
    pk[0] = bfr16(va.x); pk[1] = bfr16(va.y);
    pk[2] = bfr16(va.z); pk[3] = bfr16(va.w);
    pk[4] = bfr16(vb.x); pk[5] = bfr16(vb.y);
    pk[6] = bfr16(vb.z); pk[7] = bfr16(vb.w);
    *(int4*)(xbf + ((size_t)t * BATCH + r) * DIN + g * 128 + p * 8) = *(int4*)pk;
}

// ---------------------------------------------------------------------------
// Persistent LSTM kernel. 512 blocks x 256 thr, 2 blocks/CU (48KB LDS).
// jidx0 = L2 at t=s-1 (32 rounds of BK=64), jidx1 = L1 at t=s (20 rounds:
// 4 x-rounds from xbf + 16 h-rounds). Per round: issue next round's 6 DMA,
// s_waitcnt vmcnt(6), s_barrier, 16 MFMA, s_barrier. Flag barrier per slot.
// ---------------------------------------------------------------------------
struct PersistArgs {
    const bf16* xbf;
    const int* seqlen;
    const float* b1; const float* b2;
    const bf16* Bp1; const bf16* Bp2;
    float* c1; float* c2;
    bf16* h1; bf16* h2;
    float* hidden;
    const int* perm; const int* cnt;
    unsigned* flags;     // 512 x 32 uints (one 128B line per block)
    unsigned* release;   // 1 uint (own line)
};

#define WAITV(n) asm volatile("s_waitcnt vmcnt(" #n ")" ::: "memory")

__global__ __launch_bounds__(256, 2) void k_persist(PersistArgs P)
{
    __shared__ __align__(16) bf16 Ab[2][64 * 64];    // 2 x 8 KB
    __shared__ __align__(16) bf16 Bb[2][128 * 64];   // 2 x 16 KB

    const int jidx = blockIdx.x >> 8;
    const int bi = blockIdx.x & 255;
    const int xcd = bi & 7;
    const int sl = bi >> 3;
    const int btr = sl >> 2;
    const int btile = jidx ? (7 - btr) : btr;
    const int ntile = ((sl & 3) << 3) | xcd;
    const int b0 = btile * 64;

    const int tid = threadIdx.x;
    const int wv = tid >> 6, lane = tid & 63;
    const int n0 = ntile * 128;
    const int mw = (wv & 1) * 32;
    const int nw = (wv >> 1) * 64;
    const int c = lane & 15, q = lane >> 4;
    const size_t HS = (size_t)BATCH * H;

    const bf16* Bp    = jidx ? P.Bp1 : P.Bp2;
    const float* bias = jidx ? P.b1  : P.b2;
    float* C          = jidx ? P.c1  : P.c2;
    const int KT      = jidx ? 20 : 32;       // BK=64 rounds
    const int hcol = ntile * 32 + (wv >> 1) * 16 + c;
    const float bi_ = bias[hcol],         bf_ = bias[H + hcol];
    const float bg_ = bias[2 * H + hcol], bo_ = bias[3 * H + hcol];
    const int seg = hcol & ~127;
    const int kc_ = (hcol & 127) >> 3;
    const int jl = hcol & 7;

    int t = 0;            // current job timestep (captured by lambdas)

    // stage A tile round kt (64 rows x 64 k, pre-swizzled src, linear copy)
    auto stageA = [&](int kt, int buf) {
        const char* base; int rstride; int kbyte; bool sys;
        if (jidx) {
            if (kt < 4) { base = (const char*)(P.xbf + (size_t)t * BATCH * DIN);
                          rstride = DIN * 2; kbyte = kt * 128; sys = false; }
            else        { base = (const char*)(P.h1 + (size_t)((t + 1) & 1) * HS);
                          rstride = H * 2; kbyte = (kt - 4) * 128; sys = true; }
        } else {
            if (kt < 16) { base = (const char*)(P.h1 + (size_t)(t & 1) * HS);
                           rstride = H * 2; kbyte = kt * 128; sys = true; }
            else         { base = (const char*)(P.h2 + (size_t)((t + 1) & 1) * HS);
                           rstride = H * 2; kbyte = (kt - 16) * 128; sys = true; }
        }
        const char* gb = base + (size_t)(b0 + wv * 16) * rstride + kbyte;
        char* dst = (char*)&Ab[buf][0] + wv * 2048;
        #pragma unroll
        for (int cc = 0; cc < 2; ++cc) {
            int idx = cc * 64 + lane;
            int rloc = idx >> 3, p = idx & 7;
            const char* g = gb + (size_t)rloc * rstride + p * 16;
            if (sys) gll16_sys(g, dst + cc * 1024);
            else     gll16(g, dst + cc * 1024);
        }
    };
    // stage B tile round kt (128 cols x 64 k halves of the 256B rows)
    auto stageB = [&](int kt, int buf) {
        int kt128 = kt >> 1, half = kt & 1;
        const char* gw = (const char*)Bp + ((size_t)kt128 * NG + n0 + wv * 32) * 256 + half * 128;
        char* dst = (char*)&Bb[buf][0] + wv * 4096;
        #pragma unroll
        for (int cc = 0; cc < 4; ++cc) {
            int idx = cc * 64 + lane;
            int nloc = idx >> 3, p = idx & 7;
            gll16(gw + (size_t)nloc * 256 + p * 16, dst + cc * 1024);
        }
    };

    bool primed = false;

    for (int s = 0; s <= TSTEPS; ++s) {
        bool inrange;
        if (jidx) { t = s; inrange = (s < TSTEPS); }
        else      { t = s - 1; inrange = (s >= 1); }
        bool act = inrange && (b0 < P.cnt[t]);

        if (act) {
            if (!primed) { stageB(0, 0); primed = true; }
            stageA(0, 0);

            const accf4 zero4 = {0.f, 0.f, 0.f, 0.f};
            accf4 acc[2][4];
            #pragma unroll
            for (int i = 0; i < 2; ++i)
                #pragma unroll
                for (int j = 0; j < 4; ++j) acc[i][j] = zero4;

            for (int kt = 0; kt < KT; ++kt) {
                int buf = kt & 1;
                if (kt + 1 < KT) {
                    stageA(kt + 1, buf ^ 1);
                    stageB(kt + 1, buf ^ 1);
                    WAITV(6);                 // keep next round's 6 in flight
                } else {
                    bool nact = jidx ? ((s + 1 < TSTEPS) && b0 < P.cnt[s + 1])
                                     : ((s + 1 <= TSTEPS) && b0 < P.cnt[s]);
                    if (nact) { stageB(0, 0); WAITV(4); }   // next-slot B(0)
                    else      { WAITV(0); }
                }
                __builtin_amdgcn_s_barrier();
                __builtin_amdgcn_sched_barrier(0);
                const bf16* Acur = &Ab[buf][0];
                const bf16* Bcur = &Bb[buf][0];
                #pragma unroll
                for (int kk = 0; kk < 64; kk += 32) {
                    int kc = (kk >> 3) + q;
                    int ra = mw + c;
                    int pa = (kc ^ (ra & 7)) << 3;       // (ra+16)&7 == ra&7
                    bfrag8 af0 = *(const bfrag8*)(Acur + ra * 64 + pa);
                    bfrag8 af1 = *(const bfrag8*)(Acur + (ra + 16) * 64 + pa);
                    #pragma unroll
                    for (int nt = 0; nt < 4; ++nt) {
                        int nn = nw + nt * 16 + c;
                        bfrag8 bfv = *(const bfrag8*)(Bcur + nn * 64 + ((kc ^ (nn & 7)) << 3));
                        acc[0][nt] = __builtin_amdgcn_mfma_f32_16x16x32_bf16(af0, bfv, acc[0][nt], 0, 0, 0);
                        acc[1][nt] = __builtin_amdgcn_mfma_f32_16x16x32_bf16(af1, bfv, acc[1][nt], 0, 0, 0);
                    }
                }
                if (kt + 1 < KT) {
                    __builtin_amdgcn_sched_barrier(0);
                    __builtin_amdgcn_s_barrier();        // release buf for DMA
                    __builtin_amdgcn_sched_barrier(0);
                }
            }

            // ---- register-resident cell update (h via WT system stores) ----
            bf16* Hout = jidx ? (P.h1 + (size_t)(t & 1) * HS)
                              : (P.h2 + (size_t)(t & 1) * HS);
            #pragma unroll
            for (int mt = 0; mt < 2; ++mt) {
                #pragma unroll
                for (int reg = 0; reg < 4; ++reg) {
                    int b = b0 + mw + mt * 16 + q * 4 + reg;
                    float ig = sigm(acc[mt][0][reg] + bi_);
                    float fg = sigm(acc[mt][1][reg] + bf_);
                    float gv = tanh_f(acc[mt][2][reg] + bg_);
                    float og = sigm(acc[mt][3][reg] + bo_);
                    size_t ci = (size_t)b * H + hcol;
                    float cv = fg * C[ci] + ig * gv;
                    C[ci] = cv;                  // block-private, stays cached
                    float h = og * tanh_f(cv);
                    unsigned short hb = bfr16(h);
                    unsigned short* hp = (unsigned short*)(Hout
                        + (size_t)b * H + seg + ((kc_ ^ (b & 7)) << 3) + jl);
                    __hip_atomic_store(hp, hb, __ATOMIC_RELAXED, __HIP_MEMORY_SCOPE_SYSTEM);
                    if (jidx == 0) {
                        int pb = P.perm[b];
                        if (P.seqlen[pb] - 1 == t)
                            __hip_atomic_store(&P.hidden[(size_t)pb * H + hcol], h,
                                               __ATOMIC_RELAXED, __HIP_MEMORY_SCOPE_SYSTEM);
                    }
                }
            }
        }

        // ---- flag-based grid barrier (no RMW contention) ----
        if (s < TSTEPS) {
            WAITV(0);                         // h stores acked at MALL
            __syncthreads();
            unsigned tgt = (unsigned)(s + 1);
            if (blockIdx.x == MASTER) {
                if (tid == 0)
                    __hip_atomic_store(&P.flags[(size_t)blockIdx.x * 32], tgt,
                                       __ATOMIC_RELAXED, __HIP_MEMORY_SCOPE_SYSTEM);
                unsigned v0 = 0, v1 = 0;
                int guard = 0;
                while (true) {
                    if (v0 < tgt) v0 = __hip_atomic_load(&P.flags[(size_t)(tid * 2) * 32],
                                       __ATOMIC_RELAXED, __HIP_MEMORY_SCOPE_SYSTEM);
                    if (v1 < tgt) v1 = __hip_atomic_load(&P.flags[(size_t)(tid * 2 + 1) * 32],
                                       __ATOMIC_RELAXED, __HIP_MEMORY_SCOPE_SYSTEM);
                    if (v0 >= tgt && v1 >= tgt) break;
                    __builtin_amdgcn_s_sleep(1);
                    if (++guard > 200000) break;   // degrade, don't hang
                }
                __syncthreads();
                if (tid == 0)
                    __hip_atomic_store(P.release, tgt,
                                       __ATOMIC_RELAXED, __HIP_MEMORY_SCOPE_SYSTEM);
            } else {
                if (tid == 0) {
                    __hip_atomic_store(&P.flags[(size_t)blockIdx.x * 32], tgt,
                                       __ATOMIC_RELAXED, __HIP_MEMORY_SCOPE_SYSTEM);
                    int guard = 0;
                    while (__hip_atomic_load(P.release, __ATOMIC_RELAXED,
                                             __HIP_MEMORY_SCOPE_SYSTEM) < tgt) {
                        __builtin_amdgcn_s_sleep(1);
                        if (++guard > 200000) break;
                    }
                }
                __syncthreads();
            }
        }
    }
}

// ---------------------------------------------------------------------------
// out[b][l] = relu(hidden[b]·Wd[:,l] + bd[l]), 512 blocks x 1 wave
// ---------------------------------------------------------------------------
__global__ void k_final(const float* __restrict__ hidden, const float* __restrict__ Wd,
                        const float* __restrict__ bd, float* __restrict__ out)
{
    int b = blockIdx.x;
    int l = threadIdx.x;
    float p0 = 0.f, p1 = 0.f, p2 = 0.f;
    for (int jj = l; jj < H; jj += 64) {
        float hv = hidden[(size_t)b * H + jj];
        p0 += hv * Wd[jj * 3 + 0];
        p1 += hv * Wd[jj * 3 + 1];
        p2 += hv * Wd[jj * 3 + 2];
    }
    #pragma unroll
    for (int off = 32; off > 0; off >>= 1) {
        p0 += __shfl_down(p0, off);
        p1 += __shfl_down(p1, off);
        p2 += __shfl_down(p2, off);
    }
    if (l == 0) {
        out[b * 3 + 0] = fmaxf(p0 + bd[0], 0.f);
        out[b * 3 + 1] = fmaxf(p1 + bd[1], 0.f);
        out[b * 3 + 2] = fmaxf(p2 + bd[2], 0.f);
    }
}

extern "C" void kernel_launch(void* const* d_in, const int* in_sizes, int n_in,
                              void* d_out, int out_size, void* d_ws, size_t ws_size,
                              hipStream_t stream)
{
    const float* chars = (const float*)d_in[0];
    const int* seqlen  = (const int*)d_in[1];
    const float* W1 = (const float*)d_in[2];
    const float* U1 = (const float*)d_in[3];
    const float* b1 = (const float*)d_in[4];
    const float* W2 = (const float*)d_in[5];
    const float* U2 = (const float*)d_in[6];
    const float* b2 = (const float*)d_in[7];
    const float* Wd = (const float*)d_in[8];
    const float* bd = (const float*)d_in[9];
    float* out = (float*)d_out;

    char* ws = (char*)d_ws;
    size_t off = 0;
    bf16* Bp1 = (bf16*)(ws + off); off += (size_t)10 * NG * 128 * 2;       // 10 MB
    bf16* Bp2 = (bf16*)(ws + off); off += (size_t)16 * NG * 128 * 2;       // 16 MB
    bf16* xbf = (bf16*)(ws + off); off += (size_t)TSTEPS * BATCH * DIN * 2;// 32 MB
    bf16* h1  = (bf16*)(ws + off); off += (size_t)2 * BATCH * H * 2;       // 2 MB
    bf16* h2  = (bf16*)(ws + off); off += (size_t)2 * BATCH * H * 2;       // 2 MB
    float* c1 = (float*)(ws + off); off += (size_t)BATCH * H * 4;          // 2 MB
    float* c2 = (float*)(ws + off); off += (size_t)BATCH * H * 4;          // 2 MB
    float* hidden = (float*)(ws + off); off += (size_t)BATCH * H * 4;      // 2 MB
    int* perm = (int*)(ws + off); off += BATCH * 4;
    int* cntA = (int*)(ws + off); off += TSTEPS * 4;
    unsigned* flags = (unsigned*)(ws + off); off += (size_t)NBLK * 128;    // 64 KB
    unsigned* release = (unsigned*)(ws + off); off += 128;
    if (ws_size < off) return;  // ~68 MB needed

    (void)hipMemsetAsync(h1, 0, (size_t)2 * BATCH * H * 2, stream);
    (void)hipMemsetAsync(h2, 0, (size_t)2 * BATCH * H * 2, stream);
    (void)hipMemsetAsync(c1, 0, (size_t)BATCH * H * 4, stream);
    (void)hipMemsetAsync(c2, 0, (size_t)BATCH * H * 4, stream);
    (void)hipMemsetAsync(flags, 0, (size_t)NBLK * 128 + 128, stream);

    k_repack<<<dim3(10, 64), 64, 0, stream>>>(W1, U1, Bp1, 256);
    k_repack<<<dim3(16, 64), 64, 0, stream>>>(W2, U2, Bp2, 1024);
    k_sort<<<1, 512, 0, stream>>>(seqlen, perm, cntA);
    k_xprep<<<dim3(TSTEPS, 64), 256, 0, stream>>>(chars, perm, xbf);

    PersistArgs P;
    P.xbf = xbf; P.seqlen = seqlen;
    P.b1 = b1; P.b2 = b2;
    P.Bp1 = Bp1; P.Bp2 = Bp2;
    P.c1 = c1; P.c2 = c2;
    P.h1 = h1; P.h2 = h2;
    P.hidden = hidden;
    P.perm = perm; P.cnt = cntA;
    P.flags = flags; P.release = release;
    k_persist<<<dim3(NBLK), dim3(256), 0, stream>>>(P);

    k_final<<<512, 64, 0, stream>>>(hidden, Wd, bd, out);
}